// Round 3
// baseline (189.136 us; speedup 1.0000x reference)
//
#include <hip/hip_runtime.h>
#include <math.h>

// Problem constants (fixed by the reference):
#define B_  4
#define C_  256     // in/out channels
#define CI_ 128     // inter channels (attention head dim D)
#define N_  4096    // H*W

typedef short s16x8  __attribute__((ext_vector_type(8)));    // 8 bf16 (4 VGPRs)
typedef float f32x4  __attribute__((ext_vector_type(4)));    // 16x16 accumulator
typedef float f32x16 __attribute__((ext_vector_type(16)));   // 32x32 accumulator

// fp32 -> bf16 (RNE)
__device__ inline ushort f2bf(float f) {
    unsigned int u = __float_as_uint(f);
    u += 0x7FFF + ((u >> 16) & 1);
    return (ushort)(u >> 16);
}
__device__ inline float bf2f(ushort u) {
    return __uint_as_float(((unsigned int)u) << 16);
}

// packed f32x2 -> bf16x2 (RNE), dst[15:0]=bf16(a), dst[31:16]=bf16(b)
__device__ inline unsigned pkbf(float a, float b) {
    unsigned r;
    asm("v_cvt_pk_bf16_f32 %0, %1, %2" : "=v"(r) : "v"(a), "v"(b));
    return r;
}
// v_permlane32_swap_b32 x, y:
//   new x[32+i] = old y[i];  new y[i] = old x[32+i]   (i = 0..31)
__device__ inline void plswap(unsigned &x, unsigned &y) {
    asm volatile("v_permlane32_swap_b32 %0, %1" : "+v"(x), "+v"(y));
}

// Direct global->LDS DMA, 16B per lane. LDS dest is wave-uniform base +
// lane*16 (linear); swizzling is done on the per-lane GLOBAL source address
// (m201 both-sides pattern).
__device__ inline void gload_lds16(const void* g, void* l) {
    __builtin_amdgcn_global_load_lds(
        (const __attribute__((address_space(1))) unsigned int*)g,
        (__attribute__((address_space(3))) unsigned int*)l, 16, 0, 0);
}

// LDS-only workgroup sync: waits DS-queue drain (lgkmcnt) + rendezvous,
// WITHOUT the vmcnt(0) drain __syncthreads() forces before s_barrier.
__device__ inline void block_sync_lds() {
    asm volatile("s_waitcnt lgkmcnt(0)" ::: "memory");
    __builtin_amdgcn_s_barrier();
    asm volatile("" ::: "memory");
}

// ---------------------------------------------------------------------------
// Weight cast: Wcat = [Wg;Wt;Wp] bf16 (384x256), Wobf bf16 (256x128),
// bcat = [bg;bt;bp] fp32 (384). Grid 512x256.
// ---------------------------------------------------------------------------
__global__ __launch_bounds__(256) void wcast_kernel(
    const float* __restrict__ Wg, const float* __restrict__ Wt,
    const float* __restrict__ Wp, const float* __restrict__ Wo,
    const float* __restrict__ bg, const float* __restrict__ bt,
    const float* __restrict__ bp,
    ushort* __restrict__ Wcat, ushort* __restrict__ Wobf,
    float* __restrict__ bcat)
{
    int i = blockIdx.x * 256 + threadIdx.x;
    if (i < 32768)       Wcat[i] = f2bf(Wg[i]);
    else if (i < 65536)  Wcat[i] = f2bf(Wt[i - 32768]);
    else if (i < 98304)  Wcat[i] = f2bf(Wp[i - 65536]);
    else if (i < 131072) Wobf[i - 98304] = f2bf(Wo[i - 98304]);
    if (i < 128)         bcat[i] = bg[i];
    else if (i < 256)    bcat[i] = bt[i - 128];
    else if (i < 384)    bcat[i] = bp[i - 256];
}

// ---------------------------------------------------------------------------
// x transpose+cast: x [B][C][N] fp32 -> xT [B][N][C] bf16. Tile 64c x 64n.
// ---------------------------------------------------------------------------
__global__ __launch_bounds__(256) void xt_kernel(
    const float* __restrict__ x, ushort* __restrict__ xT)
{
    __shared__ ushort Ls[64][72];
    const int b = blockIdx.z, c0 = blockIdx.y * 64, n0 = blockIdx.x * 64;
    const float* xb = x + ((size_t)b * C_ + c0) * N_ + n0;
    const int t = threadIdx.x;
    #pragma unroll
    for (int r = 0; r < 4; r++) {
        int idx = t + 256 * r;
        int c = idx >> 4, n4 = (idx & 15) * 4;
        float4 v = *(const float4*)&xb[(size_t)c * N_ + n4];
        ushort4 o;
        o.x = f2bf(v.x); o.y = f2bf(v.y); o.z = f2bf(v.z); o.w = f2bf(v.w);
        *(ushort4*)&Ls[c][n4] = o;
    }
    __syncthreads();
    ushort* xTb = xT + ((size_t)b * N_ + n0) * C_ + c0;
    #pragma unroll
    for (int r = 0; r < 2; r++) {
        int idx = t + 256 * r;
        int n = idx >> 3, c8 = (idx & 7) * 8;
        ushort tmp[8];
        #pragma unroll
        for (int u = 0; u < 8; u++) tmp[u] = Ls[c8 + u][n];
        *(uint4*)&xTb[(size_t)n * C_ + c8] = *(uint4*)tmp;
    }
}

// ---------------------------------------------------------------------------
// Fused projection GEMM (bf16 MFMA, 16x16x32). Grid (N/64, 6, B).
// ---------------------------------------------------------------------------
__global__ __launch_bounds__(256) void proj_kernel(
    const ushort* __restrict__ Wcat, const float* __restrict__ bcat,
    const ushort* __restrict__ xT,
    ushort* __restrict__ g, ushort* __restrict__ tht, ushort* __restrict__ pht)
{
    __shared__ ushort Ws[64][72];
    __shared__ ushort Xs[64][72];
    const int b = blockIdx.z, mt = blockIdx.y, n0 = blockIdx.x * 64;
    const int t = threadIdx.x, wv = t >> 6, lane = t & 63;
    const int g4 = lane >> 4, ln = lane & 15;
    const ushort* Wsrc = Wcat + (size_t)mt * 64 * C_;
    const ushort* Xsrc = xT + ((size_t)b * N_ + n0) * C_;

    f32x4 acc[4];
    #pragma unroll
    for (int i = 0; i < 4; i++) acc[i] = (f32x4){0.f, 0.f, 0.f, 0.f};

    for (int k0 = 0; k0 < C_; k0 += 64) {
        block_sync_lds();
        #pragma unroll
        for (int r = 0; r < 2; r++) {
            int idx = t + 256 * r;
            int row = idx >> 3, k8 = (idx & 7) * 8;
            *(uint4*)&Ws[row][k8] = *(const uint4*)&Wsrc[(size_t)row * C_ + k0 + k8];
            *(uint4*)&Xs[row][k8] = *(const uint4*)&Xsrc[(size_t)row * C_ + k0 + k8];
        }
        block_sync_lds();
        if (mt < 2) {
            #pragma unroll
            for (int kk = 0; kk < 2; kk++) {
                s16x8 aW = *(const s16x8*)&Ws[16 * wv + ln][32 * kk + 8 * g4];
                #pragma unroll
                for (int nt = 0; nt < 4; nt++) {
                    s16x8 bX = *(const s16x8*)&Xs[16 * nt + ln][32 * kk + 8 * g4];
                    acc[nt] = __builtin_amdgcn_mfma_f32_16x16x32_bf16(aW, bX, acc[nt], 0, 0, 0);
                }
            }
        } else {
            #pragma unroll
            for (int kk = 0; kk < 2; kk++) {
                s16x8 aX = *(const s16x8*)&Xs[16 * wv + ln][32 * kk + 8 * g4];
                #pragma unroll
                for (int ct = 0; ct < 4; ct++) {
                    s16x8 bW = *(const s16x8*)&Ws[16 * ct + ln][32 * kk + 8 * g4];
                    acc[ct] = __builtin_amdgcn_mfma_f32_16x16x32_bf16(aX, bW, acc[ct], 0, 0, 0);
                }
            }
        }
    }

    if (mt < 2) {
        ushort* ob = g + (size_t)b * CI_ * N_;
        #pragma unroll
        for (int r = 0; r < 4; r++) {
            int mloc = 16 * wv + 4 * g4 + r;
            float bi = bcat[mt * 64 + mloc];
            #pragma unroll
            for (int nt = 0; nt < 4; nt++)
                ob[(size_t)(mt * 64 + mloc) * N_ + n0 + 16 * nt + ln] = f2bf(acc[nt][r] + bi);
        }
    } else {
        ushort* ob = ((mt < 4) ? tht : pht) + (size_t)b * N_ * CI_;
        int cib = ((mt - 2) & 1) * 64;
        #pragma unroll
        for (int r = 0; r < 4; r++) {
            int nloc = 16 * wv + 4 * g4 + r;
            #pragma unroll
            for (int ct = 0; ct < 4; ct++) {
                float bi = bcat[mt * 64 + 16 * ct + ln];
                ob[(size_t)(n0 + nloc) * CI_ + cib + 16 * ct + ln] = f2bf(acc[ct][r] + bi);
            }
        }
    }
}

// ---------------------------------------------------------------------------
// MFMA flash attention, 32x32x16, in-register softmax (T12).
// Round-3 structure: q-tile 256/block, 64 q per wave as TWO 32-q sub-blocks
// (A,B). Every K and V fragment read from LDS feeds TWO MFMAs (one per
// sub-block) -> LDS-read:MFMA ratio 1:2 (was 1:1) on the CU-shared LDS pipe.
// Double-buffered LDS (2 x 32 KB) with counted vmcnt(8) (T4): next tile's
// 8 DMAs/wave stay in flight across the whole compute phase.
// ---------------------------------------------------------------------------

// Build two PV A-fragments from the 16 in-lane scores of one 32-j S^T tile.
__device__ inline float build_pa(const f32x16& S, s16x8& f0, s16x8& f1) {
    unsigned w[8];
    #pragma unroll
    for (int e = 0; e < 8; e++)
        w[e] = pkbf(__expf(S[2 * e]), __expf(S[2 * e + 1]));
    float ls = 0.f;
    #pragma unroll
    for (int e = 0; e < 8; e++)
        ls += __uint_as_float(w[e] << 16) + __uint_as_float(w[e] & 0xFFFF0000u);
    // lane l holds p[reg] = P[q=l&31][j=(reg&3)+8*(reg>>2)+4*(l>>5)].
    plswap(w[0], w[2]);
    plswap(w[1], w[3]);
    plswap(w[4], w[6]);
    plswap(w[5], w[7]);
    union { unsigned u[4]; s16x8 v; } A, B;
    A.u[0] = w[0]; A.u[1] = w[1]; A.u[2] = w[2]; A.u[3] = w[3];
    B.u[0] = w[4]; B.u[1] = w[5]; B.u[2] = w[6]; B.u[3] = w[7];
    f0 = A.v; f1 = B.v;
    return ls;
}

// Stage one 64-j K/V tile into LDS buffer at byte offset `bufofs`.
// 8 DMA chunks of 1024 B per wave (4 K + 4 V).
#define STAGE_KV(bufofs, jsrc) do {                                          \
    _Pragma("unroll")                                                        \
    for (int r_ = 0; r_ < 4; r_++) {                                         \
        int c_   = (wv << 2) + r_;                                           \
        int row_ = (c_ << 2) + kr;                                           \
        int src_ = (((jsrc) + row_) << 8) + (kc ^ ((row_ & 7) << 4));        \
        gload_lds16(kB + src_, smemB + (bufofs) + (c_ << 10));               \
    }                                                                        \
    _Pragma("unroll")                                                        \
    for (int r_ = 0; r_ < 4; r_++) {                                         \
        int c_   = (wv << 2) + r_;                                           \
        int row_ = (c_ << 3) + vr;                                           \
        int src_ = row_ * (N_ * 2) + ((jsrc) << 1) + (vc ^ ((row_ & 7) << 4));\
        gload_lds16(vB + src_, smemB + (bufofs) + 16384 + (c_ << 10));       \
    }                                                                        \
} while (0)

template <int NC>
__global__ __launch_bounds__(256, 2) void attn_mfma_kernel(
    const ushort* __restrict__ qn,   // [B][N][CI]
    const ushort* __restrict__ kn,   // [B][N][CI]
    const ushort* __restrict__ vm,   // [B][CI][N]
    ushort* __restrict__ Opart,      // [NC][B][N][CI] bf16 (unnormalized)
    float* __restrict__ lbuf)        // [NC][B][N] row sums
{
    constexpr int JC = N_ / NC;
    // Per buffer: K [64][256B] + V [128][128B] = 32 KB; two buffers.
    __shared__ __align__(16) char smemB[65536];

    // T1: XCD-bijective chunked swizzle (nb % 8 == 0 for NC in {4,8}).
    constexpr int NI = N_ / 256;
    constexpr int nb = NI * NC * B_;
    int flat = (blockIdx.z * NC + blockIdx.y) * NI + blockIdx.x;
    int nf   = (flat & 7) * (nb / 8) + (flat >> 3);
    const int i0    = (nf % NI) * 256;
    const int chunk = (nf / NI) % NC;
    const int b     = nf / (NI * NC);
    const int jbase = chunk * JC;

    const int t    = threadIdx.x;
    const int wv   = t >> 6;
    const int lane = t & 63;
    const int n32  = lane & 31;
    const int h    = lane >> 5;
    const int swz  = (n32 & 7) << 4;   // reader-side XOR swizzle

    const char* kB = (const char*)(kn + (size_t)b * N_ * CI_);
    const char* vB = (const char*)(vm + (size_t)b * CI_ * N_);

    // ---- Q fragments straight from global. Wave owns q rows
    // [i0+64*wv, i0+64*wv+64): sub-block A = first 32, B = second 32.
    const ushort* qbw = qn + ((size_t)b * N_ + i0 + 64 * wv) * CI_;
    s16x8 aQA[8], aQB[8];
    #pragma unroll
    for (int kk = 0; kk < 8; kk++) {
        aQA[kk] = *(const s16x8*)(qbw + (size_t)n32 * CI_ + 16 * kk + 8 * h);
        aQB[kk] = *(const s16x8*)(qbw + (size_t)(32 + n32) * CI_ + 16 * kk + 8 * h);
    }

    f32x16 OA[4], OB[4];
    #pragma unroll
    for (int dt = 0; dt < 4; dt++)
        #pragma unroll
        for (int e = 0; e < 16; e++) { OA[dt][e] = 0.f; OB[dt][e] = 0.f; }
    float lsA = 0.f, lsB = 0.f;

    // stager per-lane constants
    const int kr = lane >> 4;            // K: row within 4-row chunk
    const int kc = (lane & 15) << 4;     // K: byte col 0..255
    const int vr = lane >> 3;            // V: row within 8-row chunk
    const int vc = (lane & 7) << 4;      // V: byte col 0..127

    STAGE_KV(0, jbase);
    int buf = 0;
    for (int jt = jbase; jt < jbase + JC; jt += 64) {
        if (jt + 64 < jbase + JC) {
            STAGE_KV(buf ^ 32768, jt + 64);
            asm volatile("s_waitcnt vmcnt(8)" ::: "memory");   // cur tile arrived
        } else {
            asm volatile("s_waitcnt vmcnt(0)" ::: "memory");
        }
        __builtin_amdgcn_s_barrier();
        asm volatile("" ::: "memory");

        const char* Kc = smemB + buf;
        const char* Vc = smemB + buf + 16384;

        // ======== j-half 0: K rows 0:32 ========
        {
            f32x16 SA, SB;
            #pragma unroll
            for (int e = 0; e < 16; e++) { SA[e] = 0.f; SB[e] = 0.f; }
            __builtin_amdgcn_s_setprio(1);
            #pragma unroll
            for (int kk = 0; kk < 8; kk++) {
                s16x8 aK = *(const s16x8*)(Kc + (n32 << 8) + (((kk << 5) + (h << 4)) ^ swz));
                SA = __builtin_amdgcn_mfma_f32_32x32x16_bf16(aK, aQA[kk], SA, 0, 0, 0);
                SB = __builtin_amdgcn_mfma_f32_32x32x16_bf16(aK, aQB[kk], SB, 0, 0, 0);
            }
            __builtin_amdgcn_s_setprio(0);
            s16x8 pA0, pA1, pB0, pB1;
            lsA += build_pa(SA, pA0, pA1);   // j 0..31 -> k-slots 0,1
            lsB += build_pa(SB, pB0, pB1);
            __builtin_amdgcn_s_setprio(1);
            #pragma unroll
            for (int dt = 0; dt < 4; dt++) {
                #pragma unroll
                for (int kk = 0; kk < 2; kk++) {
                    s16x8 bV = *(const s16x8*)(Vc + ((32 * dt + n32) << 7)
                                                  + (((kk << 5) + (h << 4)) ^ swz));
                    OA[dt] = __builtin_amdgcn_mfma_f32_32x32x16_bf16(
                        kk == 0 ? pA0 : pA1, bV, OA[dt], 0, 0, 0);
                    OB[dt] = __builtin_amdgcn_mfma_f32_32x32x16_bf16(
                        kk == 0 ? pB0 : pB1, bV, OB[dt], 0, 0, 0);
                }
            }
            __builtin_amdgcn_s_setprio(0);
        }

        // ======== j-half 1: K rows 32:64 ========
        {
            f32x16 SA, SB;
            #pragma unroll
            for (int e = 0; e < 16; e++) { SA[e] = 0.f; SB[e] = 0.f; }
            __builtin_amdgcn_s_setprio(1);
            #pragma unroll
            for (int kk = 0; kk < 8; kk++) {
                s16x8 aK = *(const s16x8*)(Kc + 8192 + (n32 << 8) + (((kk << 5) + (h << 4)) ^ swz));
                SA = __builtin_amdgcn_mfma_f32_32x32x16_bf16(aK, aQA[kk], SA, 0, 0, 0);
                SB = __builtin_amdgcn_mfma_f32_32x32x16_bf16(aK, aQB[kk], SB, 0, 0, 0);
            }
            __builtin_amdgcn_s_setprio(0);
            s16x8 pA2, pA3, pB2, pB3;
            lsA += build_pa(SA, pA2, pA3);   // j 32..63 -> k-slots 2,3
            lsB += build_pa(SB, pB2, pB3);
            __builtin_amdgcn_s_setprio(1);
            #pragma unroll
            for (int dt = 0; dt < 4; dt++) {
                #pragma unroll
                for (int kk = 2; kk < 4; kk++) {
                    s16x8 bV = *(const s16x8*)(Vc + ((32 * dt + n32) << 7)
                                                  + (((kk << 5) + (h << 4)) ^ swz));
                    OA[dt] = __builtin_amdgcn_mfma_f32_32x32x16_bf16(
                        kk == 2 ? pA2 : pA3, bV, OA[dt], 0, 0, 0);
                    OB[dt] = __builtin_amdgcn_mfma_f32_32x32x16_bf16(
                        kk == 2 ? pB2 : pB3, bV, OB[dt], 0, 0, 0);
                }
            }
            __builtin_amdgcn_s_setprio(0);
        }

        block_sync_lds();   // all waves done reading buf before next overwrite
        buf ^= 32768;
    }

    // ---- epilogue: unnormalized O -> [b][n][d] bf16; l -> lbuf
    ushort* Ob = Opart + (size_t)chunk * (B_ * N_ * CI_)
                       + ((size_t)b * N_ + i0 + 64 * wv) * CI_;
    #pragma unroll
    for (int rg = 0; rg < 16; rg++) {
        int R = (rg & 3) + 8 * (rg >> 2) + 4 * h;
        #pragma unroll
        for (int dt = 0; dt < 4; dt++) {
            Ob[(size_t)R * CI_ + 32 * dt + n32]        = f2bf(OA[dt][rg]);
            Ob[(size_t)(32 + R) * CI_ + 32 * dt + n32] = f2bf(OB[dt][rg]);
        }
    }
    float totA = lsA + __shfl_xor(lsA, 32);
    float totB = lsB + __shfl_xor(lsB, 32);
    if (h == 0) {
        float* lb = lbuf + ((size_t)chunk * B_ + b) * N_ + i0 + 64 * wv;
        lb[n32]      = totA;
        lb[32 + n32] = totB;
    }
}

// ---------------------------------------------------------------------------
// Output GEMM (bf16 MFMA) with fused NC-chunk combine in staging:
//   y[n][d] = (sum_c Oc)[n][d] / (sum_c lc)[n]
//   out[b,m,n] = sum_d Wo[m,d]*y[n][d] + bo[m] + x[b,m,n]
// ---------------------------------------------------------------------------
template <int NC>
__global__ __launch_bounds__(256) void outgemm_kernel(
    const ushort* __restrict__ Wobf, const float* __restrict__ bo,
    const ushort* __restrict__ Opart, const float* __restrict__ lbuf,
    const float* __restrict__ x, float* __restrict__ out)
{
    __shared__ ushort Ws[64][72];
    __shared__ ushort Ys[64][72];
    const int b = blockIdx.z, m0 = blockIdx.y * 64, n0 = blockIdx.x * 64;
    const int t = threadIdx.x, wv = t >> 6, lane = t & 63;
    const int g4 = lane >> 4, ln = lane & 15;
    const ushort* Wsrc = Wobf + (size_t)m0 * CI_;
    const size_t cs = (size_t)B_ * N_ * CI_;   // chunk stride

    f32x4 acc[4];
    #pragma unroll
    for (int i = 0; i < 4; i++) acc[i] = (f32x4){0.f, 0.f, 0.f, 0.f};

    for (int k0 = 0; k0 < CI_; k0 += 64) {
        block_sync_lds();
        #pragma unroll
        for (int r = 0; r < 2; r++) {
            int idx = t + 256 * r;
            int row = idx >> 3, k8 = (idx & 7) * 8;
            *(uint4*)&Ws[row][k8] = *(const uint4*)&Wsrc[(size_t)row * CI_ + k0 + k8];
            // fused combine: Y = (sum_c Oc) / (sum_c lc)
            size_t obase = ((size_t)b * N_ + n0 + row) * CI_ + k0 + k8;
            float lsum = 0.f;
            #pragma unroll
            for (int c = 0; c < NC; c++)
                lsum += lbuf[((size_t)c * B_ + b) * N_ + n0 + row];
            float inv = 1.0f / lsum;
            float osum[8];
            #pragma unroll
            for (int u = 0; u < 8; u++) osum[u] = 0.f;
            #pragma unroll
            for (int c = 0; c < NC; c++) {
                ushort oc[8];
                *(uint4*)oc = *(const uint4*)&Opart[(size_t)c * cs + obase];
                #pragma unroll
                for (int u = 0; u < 8; u++) osum[u] += bf2f(oc[u]);
            }
            ushort yo[8];
            #pragma unroll
            for (int u = 0; u < 8; u++) yo[u] = f2bf(osum[u] * inv);
            *(uint4*)&Ys[row][k8] = *(uint4*)yo;
        }
        block_sync_lds();
        #pragma unroll
        for (int kk = 0; kk < 2; kk++) {
            s16x8 aW = *(const s16x8*)&Ws[16 * wv + ln][32 * kk + 8 * g4];
            #pragma unroll
            for (int nt = 0; nt < 4; nt++) {
                s16x8 bY = *(const s16x8*)&Ys[16 * nt + ln][32 * kk + 8 * g4];
                acc[nt] = __builtin_amdgcn_mfma_f32_16x16x32_bf16(aW, bY, acc[nt], 0, 0, 0);
            }
        }
    }

    float* outb = out + (size_t)b * C_ * N_;
    const float* xb = x + (size_t)b * C_ * N_;
    #pragma unroll
    for (int r = 0; r < 4; r++) {
        int m = m0 + 16 * wv + 4 * g4 + r;
        float bi = bo[m];
        #pragma unroll
        for (int nt = 0; nt < 4; nt++) {
            size_t idx = (size_t)m * N_ + n0 + 16 * nt + ln;
            outb[idx] = acc[nt][r] + bi + xb[idx];
        }
    }
}

// ---------------------------------------------------------------------------
extern "C" void kernel_launch(void* const* d_in, const int* in_sizes, int n_in,
                              void* d_out, int out_size, void* d_ws, size_t ws_size,
                              hipStream_t stream) {
    const float* x  = (const float*)d_in[0];
    const float* Wg = (const float*)d_in[1];
    const float* bg = (const float*)d_in[2];
    const float* Wt = (const float*)d_in[3];
    const float* bt = (const float*)d_in[4];
    const float* Wp = (const float*)d_in[5];
    const float* bp = (const float*)d_in[6];
    const float* Wo = (const float*)d_in[7];
    const float* bo = (const float*)d_in[8];
    float* out = (float*)d_out;

    // NC=8 needs 46,925,312 B of workspace; fall back to NC=4 (29.9 MB)
    // if the harness workspace is smaller.
    const bool big = ws_size >= 46925312ull;
    const int NC = big ? 8 : 4;

    char* w = (char*)d_ws;
    size_t opart_sz = (size_t)NC * B_ * N_ * CI_ * sizeof(ushort);
    ushort* xT    = (ushort*)w;                        // [B][N][C] bf16, 8MB (dead after proj)
    ushort* Opart = (ushort*)w;                        // [NC][B][N][CI] bf16 (aliases xT)
    ushort* g     = (ushort*)(w + opart_sz);           // [B][CI][N] bf16, 4MB
    ushort* tht   = (ushort*)(w + opart_sz + 4194304); // [B][N][CI] bf16, 4MB
    ushort* pht   = (ushort*)(w + opart_sz + 8388608); // [B][N][CI] bf16, 4MB
    ushort* Wcat  = (ushort*)(w + opart_sz + 12582912);          // [384][256] bf16
    ushort* Wobf  = (ushort*)(w + opart_sz + 12582912 + 196608); // [256][128] bf16
    float*  bcat  = (float*) (w + opart_sz + 12582912 + 262144); // [384]
    float*  lbuf  = (float*) (w + opart_sz + 12582912 + 263680); // [NC][B][N] fp32

    dim3 blk(256);
    wcast_kernel<<<512, blk, 0, stream>>>(Wg, Wt, Wp, Wo, bg, bt, bp, Wcat, Wobf, bcat);
    xt_kernel<<<dim3(N_ / 64, C_ / 64, B_), blk, 0, stream>>>(x, xT);
    proj_kernel<<<dim3(N_ / 64, 6, B_), blk, 0, stream>>>(Wcat, bcat, xT, g, tht, pht);
    if (big) {
        attn_mfma_kernel<8><<<dim3(N_ / 256, 8, B_), blk, 0, stream>>>(tht, pht, g, Opart, lbuf);
        outgemm_kernel<8><<<dim3(N_ / 64, C_ / 64, B_), blk, 0, stream>>>(Wobf, bo, Opart, lbuf, x, out);
    } else {
        attn_mfma_kernel<4><<<dim3(N_ / 256, 4, B_), blk, 0, stream>>>(tht, pht, g, Opart, lbuf);
        outgemm_kernel<4><<<dim3(N_ / 64, C_ / 64, B_), blk, 0, stream>>>(Wobf, bo, Opart, lbuf, x, out);
    }
}

// Round 4
// 150.852 us; speedup vs baseline: 1.2538x; 1.2538x over previous
//
#include <hip/hip_runtime.h>
#include <math.h>

// Problem constants (fixed by the reference):
#define B_  4
#define C_  256     // in/out channels
#define CI_ 128     // inter channels (attention head dim D)
#define N_  4096    // H*W

typedef short s16x8  __attribute__((ext_vector_type(8)));    // 8 bf16 (4 VGPRs)
typedef float f32x4  __attribute__((ext_vector_type(4)));    // 16x16 accumulator
typedef float f32x16 __attribute__((ext_vector_type(16)));   // 32x32 accumulator

// fp32 -> bf16 (RNE)
__device__ inline ushort f2bf(float f) {
    unsigned int u = __float_as_uint(f);
    u += 0x7FFF + ((u >> 16) & 1);
    return (ushort)(u >> 16);
}
__device__ inline float bf2f(ushort u) {
    return __uint_as_float(((unsigned int)u) << 16);
}

// packed f32x2 -> bf16x2 (RNE)
__device__ inline unsigned pkbf(float a, float b) {
    unsigned r;
    asm("v_cvt_pk_bf16_f32 %0, %1, %2" : "=v"(r) : "v"(a), "v"(b));
    return r;
}
// v_permlane32_swap_b32 x, y
__device__ inline void plswap(unsigned &x, unsigned &y) {
    asm volatile("v_permlane32_swap_b32 %0, %1" : "+v"(x), "+v"(y));
}

// Direct global->LDS DMA, 16B per lane (linear dest, source pre-swizzled).
__device__ inline void gload_lds16(const void* g, void* l) {
    __builtin_amdgcn_global_load_lds(
        (const __attribute__((address_space(1))) unsigned int*)g,
        (__attribute__((address_space(3))) unsigned int*)l, 16, 0, 0);
}

// LDS-only workgroup sync (no vmcnt drain).
__device__ inline void block_sync_lds() {
    asm volatile("s_waitcnt lgkmcnt(0)" ::: "memory");
    __builtin_amdgcn_s_barrier();
    asm volatile("" ::: "memory");
}

// ---------------------------------------------------------------------------
// Prep kernel: fuses weight cast (blocks 0..511) and x transpose+cast
// (blocks 512..1535). Saves one launch gap.
// ---------------------------------------------------------------------------
__global__ __launch_bounds__(256) void prep_kernel(
    const float* __restrict__ Wg, const float* __restrict__ Wt,
    const float* __restrict__ Wp, const float* __restrict__ Wo,
    const float* __restrict__ bg, const float* __restrict__ bt,
    const float* __restrict__ bp,
    ushort* __restrict__ Wcat, ushort* __restrict__ Wobf,
    float* __restrict__ bcat,
    const float* __restrict__ x, ushort* __restrict__ xT)
{
    __shared__ ushort Ls[64][72];
    const int bid = blockIdx.x;
    const int t = threadIdx.x;
    if (bid < 512) {
        int i = bid * 256 + t;
        if (i < 32768)       Wcat[i] = f2bf(Wg[i]);
        else if (i < 65536)  Wcat[i] = f2bf(Wt[i - 32768]);
        else if (i < 98304)  Wcat[i] = f2bf(Wp[i - 65536]);
        else if (i < 131072) Wobf[i - 98304] = f2bf(Wo[i - 98304]);
        if (i < 128)         bcat[i] = bg[i];
        else if (i < 256)    bcat[i] = bt[i - 128];
        else if (i < 384)    bcat[i] = bp[i - 256];
        return;
    }
    // xt part: decode (64, 4, 4)
    int idx2 = bid - 512;
    const int n0 = (idx2 & 63) * 64;
    const int c0 = ((idx2 >> 6) & 3) * 64;
    const int b  = idx2 >> 8;
    const float* xb = x + ((size_t)b * C_ + c0) * N_ + n0;
    #pragma unroll
    for (int r = 0; r < 4; r++) {
        int idx = t + 256 * r;
        int c = idx >> 4, n4 = (idx & 15) * 4;
        float4 v = *(const float4*)&xb[(size_t)c * N_ + n4];
        ushort4 o;
        o.x = f2bf(v.x); o.y = f2bf(v.y); o.z = f2bf(v.z); o.w = f2bf(v.w);
        *(ushort4*)&Ls[c][n4] = o;
    }
    __syncthreads();
    ushort* xTb = xT + ((size_t)b * N_ + n0) * C_ + c0;
    #pragma unroll
    for (int r = 0; r < 2; r++) {
        int idx = t + 256 * r;
        int n = idx >> 3, c8 = (idx & 7) * 8;
        ushort tmp[8];
        #pragma unroll
        for (int u = 0; u < 8; u++) tmp[u] = Ls[c8 + u][n];
        *(uint4*)&xTb[(size_t)n * C_ + c8] = *(uint4*)tmp;
    }
}

// ---------------------------------------------------------------------------
// Fused projection GEMM (bf16 MFMA, 16x16x32), 3-way mt-merged.
// Grid (N/64, 2, B). Block yy handles mt = {yy, 2+yy, 4+yy}: one g-tile and
// two transposed tiles (tht ci-half yy, pht ci-half yy). X tile staged ONCE
// per 3 output tiles (was 6 separate blocks); 24 MFMA/wave/k-iter.
// ---------------------------------------------------------------------------
__global__ __launch_bounds__(256) void proj_kernel(
    const ushort* __restrict__ Wcat, const float* __restrict__ bcat,
    const ushort* __restrict__ xT,
    ushort* __restrict__ g, ushort* __restrict__ tht, ushort* __restrict__ pht)
{
    __shared__ ushort Ws[192][72];   // rows 0..63: mt=yy; 64..127: mt=2+yy; 128..191: mt=4+yy
    __shared__ ushort Xs[64][72];
    const int b = blockIdx.z, yy = blockIdx.y, n0 = blockIdx.x * 64;
    const int t = threadIdx.x, wv = t >> 6, lane = t & 63;
    const int g4 = lane >> 4, ln = lane & 15;
    const ushort* Xsrc = xT + ((size_t)b * N_ + n0) * C_;

    f32x4 accg[4], acct[2][4];
    #pragma unroll
    for (int i = 0; i < 4; i++) {
        accg[i] = (f32x4){0.f, 0.f, 0.f, 0.f};
        acct[0][i] = (f32x4){0.f, 0.f, 0.f, 0.f};
        acct[1][i] = (f32x4){0.f, 0.f, 0.f, 0.f};
    }

    for (int k0 = 0; k0 < C_; k0 += 64) {
        block_sync_lds();
        // stage W: 192 rows x 64k (6 chunks/thread)
        #pragma unroll
        for (int r = 0; r < 6; r++) {
            int idx = t + 256 * r;
            int row = idx >> 3, k8 = (idx & 7) * 8;
            int srow = ((row >> 6) * 2 + yy) * 64 + (row & 63);
            *(uint4*)&Ws[row][k8] = *(const uint4*)&Wcat[(size_t)srow * C_ + k0 + k8];
        }
        // stage X: 64 rows x 64k (2 chunks/thread)
        #pragma unroll
        for (int r = 0; r < 2; r++) {
            int idx = t + 256 * r;
            int row = idx >> 3, k8 = (idx & 7) * 8;
            *(uint4*)&Xs[row][k8] = *(const uint4*)&Xsrc[(size_t)row * C_ + k0 + k8];
        }
        block_sync_lds();
        #pragma unroll
        for (int kk = 0; kk < 2; kk++) {
            // g-type (mt = yy): A = W-row, B = X-row
            s16x8 aW = *(const s16x8*)&Ws[16 * wv + ln][32 * kk + 8 * g4];
            #pragma unroll
            for (int nt = 0; nt < 4; nt++) {
                s16x8 bX = *(const s16x8*)&Xs[16 * nt + ln][32 * kk + 8 * g4];
                accg[nt] = __builtin_amdgcn_mfma_f32_16x16x32_bf16(aW, bX, accg[nt], 0, 0, 0);
            }
            // t-type (mt = 2+yy, 4+yy): A = X-row, B = W-row
            s16x8 aX = *(const s16x8*)&Xs[16 * wv + ln][32 * kk + 8 * g4];
            #pragma unroll
            for (int mi = 0; mi < 2; mi++) {
                #pragma unroll
                for (int ct = 0; ct < 4; ct++) {
                    s16x8 bW = *(const s16x8*)&Ws[64 + 64 * mi + 16 * ct + ln][32 * kk + 8 * g4];
                    acct[mi][ct] = __builtin_amdgcn_mfma_f32_16x16x32_bf16(aX, bW, acct[mi][ct], 0, 0, 0);
                }
            }
        }
    }

    // epilogue: g tile (mt = yy)
    {
        ushort* ob = g + (size_t)b * CI_ * N_;
        #pragma unroll
        for (int r = 0; r < 4; r++) {
            int mloc = 16 * wv + 4 * g4 + r;
            float bi = bcat[yy * 64 + mloc];
            #pragma unroll
            for (int nt = 0; nt < 4; nt++)
                ob[(size_t)(yy * 64 + mloc) * N_ + n0 + 16 * nt + ln] = f2bf(accg[nt][r] + bi);
        }
    }
    // epilogue: tht (mi=0) / pht (mi=1), ci-half = yy*64
    #pragma unroll
    for (int mi = 0; mi < 2; mi++) {
        int mt = 2 + 2 * mi + yy;
        ushort* ob = (mi == 0 ? tht : pht) + (size_t)b * N_ * CI_;
        int cib = yy * 64;
        #pragma unroll
        for (int r = 0; r < 4; r++) {
            int nloc = 16 * wv + 4 * g4 + r;
            #pragma unroll
            for (int ct = 0; ct < 4; ct++) {
                float bi = bcat[mt * 64 + 16 * ct + ln];
                ob[(size_t)(n0 + nloc) * CI_ + cib + 16 * ct + ln] = f2bf(acct[mi][ct][r] + bi);
            }
        }
    }
}

// ---------------------------------------------------------------------------
// MFMA flash attention, 32x32x16, in-register softmax (T12), gload_lds
// staging (T2 both-sides 8-slot swizzle), XCD swizzle (T1). R2 structure
// (32q/wave, no A/B doubling -> no spill) + double-buffered LDS with
// counted vmcnt(8) (T4). NC=4.
// ---------------------------------------------------------------------------

// Build two PV A-fragments from the 16 in-lane scores of one 32-j S^T tile.
__device__ inline float build_pa(const f32x16& S, s16x8& f0, s16x8& f1) {
    unsigned w[8];
    #pragma unroll
    for (int e = 0; e < 8; e++)
        w[e] = pkbf(__expf(S[2 * e]), __expf(S[2 * e + 1]));
    float ls = 0.f;
    #pragma unroll
    for (int e = 0; e < 8; e++)
        ls += __uint_as_float(w[e] << 16) + __uint_as_float(w[e] & 0xFFFF0000u);
    plswap(w[0], w[2]);
    plswap(w[1], w[3]);
    plswap(w[4], w[6]);
    plswap(w[5], w[7]);
    union { unsigned u[4]; s16x8 v; } A, B;
    A.u[0] = w[0]; A.u[1] = w[1]; A.u[2] = w[2]; A.u[3] = w[3];
    B.u[0] = w[4]; B.u[1] = w[5]; B.u[2] = w[6]; B.u[3] = w[7];
    f0 = A.v; f1 = B.v;
    return ls;
}

// Stage one 64-j K/V tile into LDS buffer at byte offset `bufofs`.
#define STAGE_KV(bufofs, jsrc) do {                                          \
    _Pragma("unroll")                                                        \
    for (int r_ = 0; r_ < 4; r_++) {                                         \
        int c_   = (wv << 2) + r_;                                           \
        int row_ = (c_ << 2) + kr;                                           \
        int src_ = (((jsrc) + row_) << 8) + (kc ^ ((row_ & 7) << 4));        \
        gload_lds16(kB + src_, smemB + (bufofs) + (c_ << 10));               \
    }                                                                        \
    _Pragma("unroll")                                                        \
    for (int r_ = 0; r_ < 4; r_++) {                                         \
        int c_   = (wv << 2) + r_;                                           \
        int row_ = (c_ << 3) + vr;                                           \
        int src_ = row_ * (N_ * 2) + ((jsrc) << 1) + (vc ^ ((row_ & 7) << 4));\
        gload_lds16(vB + src_, smemB + (bufofs) + 16384 + (c_ << 10));       \
    }                                                                        \
} while (0)

#define NC_ 4
#define JC_ (N_ / NC_)

__global__ __launch_bounds__(256, 2) void attn_mfma_kernel(
    const ushort* __restrict__ qn,   // [B][N][CI]
    const ushort* __restrict__ kn,   // [B][N][CI]
    const ushort* __restrict__ vm,   // [B][CI][N]
    ushort* __restrict__ Opart,      // [NC][B][N][CI] bf16 (unnormalized)
    float* __restrict__ lbuf)        // [NC][B][N] row sums
{
    // Per buffer: K [64][256B] + V [128][128B] = 32 KB; two buffers.
    __shared__ __align__(16) char smemB[65536];

    // T1: XCD-bijective chunked swizzle (nb = 512, divisible by 8).
    constexpr int NI = N_ / 128;
    constexpr int nb = NI * NC_ * B_;
    int flat = (blockIdx.z * NC_ + blockIdx.y) * NI + blockIdx.x;
    int nf   = (flat & 7) * (nb / 8) + (flat >> 3);
    const int i0    = (nf % NI) * 128;
    const int chunk = (nf / NI) % NC_;
    const int b     = nf / (NI * NC_);
    const int jbase = chunk * JC_;

    const int t    = threadIdx.x;
    const int wv   = t >> 6;
    const int lane = t & 63;
    const int n32  = lane & 31;
    const int h    = lane >> 5;
    const int swz  = (n32 & 7) << 4;   // reader-side XOR swizzle

    const char* kB = (const char*)(kn + (size_t)b * N_ * CI_);
    const char* vB = (const char*)(vm + (size_t)b * CI_ * N_);

    // Q fragments straight from global: lane's q-row = 32*wv + n32.
    const ushort* qb = qn + ((size_t)b * N_ + i0) * CI_;
    s16x8 aQ[8];
    #pragma unroll
    for (int kk = 0; kk < 8; kk++)
        aQ[kk] = *(const s16x8*)(qb + (size_t)(32 * wv + n32) * CI_ + 16 * kk + 8 * h);

    f32x16 Oacc[4];
    #pragma unroll
    for (int dt = 0; dt < 4; dt++)
        #pragma unroll
        for (int e = 0; e < 16; e++) Oacc[dt][e] = 0.f;
    float lsum = 0.f;

    // stager per-lane constants
    const int kr = lane >> 4;            // K: row within 4-row chunk
    const int kc = (lane & 15) << 4;     // K: byte col 0..255
    const int vr = lane >> 3;            // V: row within 8-row chunk
    const int vc = (lane & 7) << 4;      // V: byte col 0..127

    STAGE_KV(0, jbase);
    int buf = 0;
    for (int jt = jbase; jt < jbase + JC_; jt += 64) {
        if (jt + 64 < jbase + JC_) {
            STAGE_KV(buf ^ 32768, jt + 64);
            asm volatile("s_waitcnt vmcnt(8)" ::: "memory");   // cur tile arrived
        } else {
            asm volatile("s_waitcnt vmcnt(0)" ::: "memory");
        }
        __builtin_amdgcn_s_barrier();
        asm volatile("" ::: "memory");

        const char* Kc = smemB + buf;
        const char* Vc = smemB + buf + 16384;

        // ---- S0^T = K[0:32] Q^T, softmax0 (S0 dies before S1 lives)
        s16x8 pa[4];
        {
            f32x16 S0;
            #pragma unroll
            for (int e = 0; e < 16; e++) S0[e] = 0.f;
            __builtin_amdgcn_s_setprio(1);
            #pragma unroll
            for (int kk = 0; kk < 8; kk++) {
                s16x8 aK = *(const s16x8*)(Kc + (n32 << 8) + (((kk << 5) + (h << 4)) ^ swz));
                S0 = __builtin_amdgcn_mfma_f32_32x32x16_bf16(aK, aQ[kk], S0, 0, 0, 0);
            }
            __builtin_amdgcn_s_setprio(0);
            lsum += build_pa(S0, pa[0], pa[1]);   // j 0..31 -> k-slots 0,1
        }
        // ---- S1^T = K[32:64] Q^T, softmax1
        {
            f32x16 S1;
            #pragma unroll
            for (int e = 0; e < 16; e++) S1[e] = 0.f;
            __builtin_amdgcn_s_setprio(1);
            #pragma unroll
            for (int kk = 0; kk < 8; kk++) {
                s16x8 aK = *(const s16x8*)(Kc + 8192 + (n32 << 8) + (((kk << 5) + (h << 4)) ^ swz));
                S1 = __builtin_amdgcn_mfma_f32_32x32x16_bf16(aK, aQ[kk], S1, 0, 0, 0);
            }
            __builtin_amdgcn_s_setprio(0);
            lsum += build_pa(S1, pa[2], pa[3]);   // j 32..63 -> k-slots 2,3
        }

        // ---- PV: O[32q x 128d] += P[32q x 64j] V[64j x 128d]
        __builtin_amdgcn_s_setprio(1);
        #pragma unroll
        for (int dt = 0; dt < 4; dt++) {
            #pragma unroll
            for (int kk = 0; kk < 4; kk++) {
                s16x8 bV = *(const s16x8*)(Vc + ((32 * dt + n32) << 7)
                                              + (((kk << 5) + (h << 4)) ^ swz));
                Oacc[dt] = __builtin_amdgcn_mfma_f32_32x32x16_bf16(pa[kk], bV, Oacc[dt], 0, 0, 0);
            }
        }
        __builtin_amdgcn_s_setprio(0);

        block_sync_lds();   // all waves done reading buf before it's restaged
        buf ^= 32768;
    }

    // ---- epilogue
    ushort* Ob = Opart + (size_t)chunk * (B_ * N_ * CI_) + ((size_t)b * N_ + i0) * CI_;
    #pragma unroll
    for (int rg = 0; rg < 16; rg++) {
        int R = (rg & 3) + 8 * (rg >> 2) + 4 * h;
        int q = 32 * wv + R;
        #pragma unroll
        for (int dt = 0; dt < 4; dt++)
            Ob[(size_t)q * CI_ + 32 * dt + n32] = f2bf(Oacc[dt][rg]);
    }
    float ot  = __shfl_xor(lsum, 32);
    float tot = lsum + ot;
    if (h == 0)
        lbuf[((size_t)chunk * B_ + b) * N_ + i0 + 32 * wv + n32] = tot;
}

// ---------------------------------------------------------------------------
// Output GEMM (bf16 MFMA) with fused 4-chunk combine in staging.
// ---------------------------------------------------------------------------
__global__ __launch_bounds__(256) void outgemm_kernel(
    const ushort* __restrict__ Wobf, const float* __restrict__ bo,
    const ushort* __restrict__ Opart, const float* __restrict__ lbuf,
    const float* __restrict__ x, float* __restrict__ out)
{
    __shared__ ushort Ws[64][72];
    __shared__ ushort Ys[64][72];
    const int b = blockIdx.z, m0 = blockIdx.y * 64, n0 = blockIdx.x * 64;
    const int t = threadIdx.x, wv = t >> 6, lane = t & 63;
    const int g4 = lane >> 4, ln = lane & 15;
    const ushort* Wsrc = Wobf + (size_t)m0 * CI_;
    const size_t cs = (size_t)B_ * N_ * CI_;   // chunk stride

    f32x4 acc[4];
    #pragma unroll
    for (int i = 0; i < 4; i++) acc[i] = (f32x4){0.f, 0.f, 0.f, 0.f};

    for (int k0 = 0; k0 < CI_; k0 += 64) {
        block_sync_lds();
        #pragma unroll
        for (int r = 0; r < 2; r++) {
            int idx = t + 256 * r;
            int row = idx >> 3, k8 = (idx & 7) * 8;
            *(uint4*)&Ws[row][k8] = *(const uint4*)&Wsrc[(size_t)row * CI_ + k0 + k8];
            size_t obase = ((size_t)b * N_ + n0 + row) * CI_ + k0 + k8;
            float lsum = 0.f;
            #pragma unroll
            for (int c = 0; c < NC_; c++)
                lsum += lbuf[((size_t)c * B_ + b) * N_ + n0 + row];
            float inv = 1.0f / lsum;
            float osum[8];
            #pragma unroll
            for (int u = 0; u < 8; u++) osum[u] = 0.f;
            #pragma unroll
            for (int c = 0; c < NC_; c++) {
                ushort oc[8];
                *(uint4*)oc = *(const uint4*)&Opart[(size_t)c * cs + obase];
                #pragma unroll
                for (int u = 0; u < 8; u++) osum[u] += bf2f(oc[u]);
            }
            ushort yo[8];
            #pragma unroll
            for (int u = 0; u < 8; u++) yo[u] = f2bf(osum[u] * inv);
            *(uint4*)&Ys[row][k8] = *(uint4*)yo;
        }
        block_sync_lds();
        #pragma unroll
        for (int kk = 0; kk < 2; kk++) {
            s16x8 aW = *(const s16x8*)&Ws[16 * wv + ln][32 * kk + 8 * g4];
            #pragma unroll
            for (int nt = 0; nt < 4; nt++) {
                s16x8 bY = *(const s16x8*)&Ys[16 * nt + ln][32 * kk + 8 * g4];
                acc[nt] = __builtin_amdgcn_mfma_f32_16x16x32_bf16(aW, bY, acc[nt], 0, 0, 0);
            }
        }
    }

    float* outb = out + (size_t)b * C_ * N_;
    const float* xb = x + (size_t)b * C_ * N_;
    #pragma unroll
    for (int r = 0; r < 4; r++) {
        int m = m0 + 16 * wv + 4 * g4 + r;
        float bi = bo[m];
        #pragma unroll
        for (int nt = 0; nt < 4; nt++) {
            size_t idx = (size_t)m * N_ + n0 + 16 * nt + ln;
            outb[idx] = acc[nt][r] + bi + xb[idx];
        }
    }
}

// ---------------------------------------------------------------------------
extern "C" void kernel_launch(void* const* d_in, const int* in_sizes, int n_in,
                              void* d_out, int out_size, void* d_ws, size_t ws_size,
                              hipStream_t stream) {
    const float* x  = (const float*)d_in[0];
    const float* Wg = (const float*)d_in[1];
    const float* bg = (const float*)d_in[2];
    const float* Wt = (const float*)d_in[3];
    const float* bt = (const float*)d_in[4];
    const float* Wp = (const float*)d_in[5];
    const float* bp = (const float*)d_in[6];
    const float* Wo = (const float*)d_in[7];
    const float* bo = (const float*)d_in[8];
    float* out = (float*)d_out;

    // ws layout (bytes), NC=4. xT (8 MB) dead after proj; Opart aliases it.
    char* w = (char*)d_ws;
    ushort* xT    = (ushort*)w;                   // [B][N][C]  bf16, 8 MB
    ushort* Opart = (ushort*)w;                   // [4][B][N][CI] bf16, 16 MB
    ushort* g     = (ushort*)(w + 16777216);      // [B][CI][N] bf16, 4 MB
    ushort* tht   = (ushort*)(w + 20971520);      // [B][N][CI] bf16, 4 MB
    ushort* pht   = (ushort*)(w + 25165824);      // [B][N][CI] bf16, 4 MB
    ushort* Wcat  = (ushort*)(w + 29360128);      // [384][256] bf16
    ushort* Wobf  = (ushort*)(w + 29556736);      // [256][128] bf16
    float*  bcat  = (float*) (w + 29622272);      // [384]
    float*  lbuf  = (float*) (w + 29623808);      // [4][B][N] fp32, 256 KB

    dim3 blk(256);
    prep_kernel<<<1536, blk, 0, stream>>>(Wg, Wt, Wp, Wo, bg, bt, bp,
                                          Wcat, Wobf, bcat, x, xT);
    proj_kernel<<<dim3(N_ / 64, 2, B_), blk, 0, stream>>>(Wcat, bcat, xT, g, tht, pht);
    attn_mfma_kernel<<<dim3(N_ / 128, NC_, B_), blk, 0, stream>>>(tht, pht, g, Opart, lbuf);
    outgemm_kernel<<<dim3(N_ / 64, C_ / 64, B_), blk, 0, stream>>>(Wobf, bo, Opart, lbuf, x, out);
}

// Round 5
// 145.351 us; speedup vs baseline: 1.3012x; 1.0378x over previous
//
#include <hip/hip_runtime.h>
#include <math.h>

// Problem constants (fixed by the reference):
#define B_  4
#define C_  256     // in/out channels
#define CI_ 128     // inter channels (attention head dim D)
#define N_  4096    // H*W

typedef short s16x8  __attribute__((ext_vector_type(8)));    // 8 bf16 (4 VGPRs)
typedef float f32x4  __attribute__((ext_vector_type(4)));    // 16x16 accumulator
typedef float f32x16 __attribute__((ext_vector_type(16)));   // 32x32 accumulator

// fp32 -> bf16 (RNE)
__device__ inline ushort f2bf(float f) {
    unsigned int u = __float_as_uint(f);
    u += 0x7FFF + ((u >> 16) & 1);
    return (ushort)(u >> 16);
}
__device__ inline float bf2f(ushort u) {
    return __uint_as_float(((unsigned int)u) << 16);
}

// packed f32x2 -> bf16x2 (RNE)
__device__ inline unsigned pkbf(float a, float b) {
    unsigned r;
    asm("v_cvt_pk_bf16_f32 %0, %1, %2" : "=v"(r) : "v"(a), "v"(b));
    return r;
}
// v_permlane32_swap_b32 x, y
__device__ inline void plswap(unsigned &x, unsigned &y) {
    asm volatile("v_permlane32_swap_b32 %0, %1" : "+v"(x), "+v"(y));
}

// Direct global->LDS DMA, 16B per lane (linear dest, source pre-swizzled).
__device__ inline void gload_lds16(const void* g, void* l) {
    __builtin_amdgcn_global_load_lds(
        (const __attribute__((address_space(1))) unsigned int*)g,
        (__attribute__((address_space(3))) unsigned int*)l, 16, 0, 0);
}

// LDS-only workgroup sync (no vmcnt drain).
__device__ inline void block_sync_lds() {
    asm volatile("s_waitcnt lgkmcnt(0)" ::: "memory");
    __builtin_amdgcn_s_barrier();
    asm volatile("" ::: "memory");
}

// ---------------------------------------------------------------------------
// Prep kernel: fuses weight cast (blocks 0..511) and x transpose+cast
// (blocks 512..1535).
// ---------------------------------------------------------------------------
__global__ __launch_bounds__(256) void prep_kernel(
    const float* __restrict__ Wg, const float* __restrict__ Wt,
    const float* __restrict__ Wp, const float* __restrict__ Wo,
    const float* __restrict__ bg, const float* __restrict__ bt,
    const float* __restrict__ bp,
    ushort* __restrict__ Wcat, ushort* __restrict__ Wobf,
    float* __restrict__ bcat,
    const float* __restrict__ x, ushort* __restrict__ xT)
{
    __shared__ ushort Ls[64][72];
    const int bid = blockIdx.x;
    const int t = threadIdx.x;
    if (bid < 512) {
        int i = bid * 256 + t;
        if (i < 32768)       Wcat[i] = f2bf(Wg[i]);
        else if (i < 65536)  Wcat[i] = f2bf(Wt[i - 32768]);
        else if (i < 98304)  Wcat[i] = f2bf(Wp[i - 65536]);
        else if (i < 131072) Wobf[i - 98304] = f2bf(Wo[i - 98304]);
        if (i < 128)         bcat[i] = bg[i];
        else if (i < 256)    bcat[i] = bt[i - 128];
        else if (i < 384)    bcat[i] = bp[i - 256];
        return;
    }
    // xt part: decode (64, 4, 4)
    int idx2 = bid - 512;
    const int n0 = (idx2 & 63) * 64;
    const int c0 = ((idx2 >> 6) & 3) * 64;
    const int b  = idx2 >> 8;
    const float* xb = x + ((size_t)b * C_ + c0) * N_ + n0;
    #pragma unroll
    for (int r = 0; r < 4; r++) {
        int idx = t + 256 * r;
        int c = idx >> 4, n4 = (idx & 15) * 4;
        float4 v = *(const float4*)&xb[(size_t)c * N_ + n4];
        ushort4 o;
        o.x = f2bf(v.x); o.y = f2bf(v.y); o.z = f2bf(v.z); o.w = f2bf(v.w);
        *(ushort4*)&Ls[c][n4] = o;
    }
    __syncthreads();
    ushort* xTb = xT + ((size_t)b * N_ + n0) * C_ + c0;
    #pragma unroll
    for (int r = 0; r < 2; r++) {
        int idx = t + 256 * r;
        int n = idx >> 3, c8 = (idx & 7) * 8;
        ushort tmp[8];
        #pragma unroll
        for (int u = 0; u < 8; u++) tmp[u] = Ls[c8 + u][n];
        *(uint4*)&xTb[(size_t)n * C_ + c8] = *(uint4*)tmp;
    }
}

// ---------------------------------------------------------------------------
// Projection GEMM v2: 128x128 tile, BK=64, double-buffered gload_lds
// staging (pre-swizzled source, XOR-swizzled ds_read), counted vmcnt(8).
// Grid (N/128, 3, B): mt=0 -> g [CI][N]; mt=1 -> tht [N][CI]; mt=2 -> pht.
// C[m][n] = sum_k Wcat[mt*128+m][k] * xT[n][k], K=256.
// ---------------------------------------------------------------------------
__global__ __launch_bounds__(256, 2) void proj_kernel(
    const ushort* __restrict__ Wcat, const float* __restrict__ bcat,
    const ushort* __restrict__ xT,
    ushort* __restrict__ g, ushort* __restrict__ tht, ushort* __restrict__ pht)
{
    // per buffer: A 128x128B (16 KB) + B 128x128B (16 KB); two buffers.
    __shared__ __align__(16) char smem[65536];
    const int b = blockIdx.z, mt = blockIdx.y, n0 = blockIdx.x * 128;
    const int t = threadIdx.x, wv = t >> 6, lane = t & 63;
    const int wr = wv >> 1, wc = wv & 1;          // 2x2 wave grid
    const int g4 = lane >> 4, ln = lane & 15;

    const char* Asrc = (const char*)(Wcat + (size_t)mt * 128 * C_);  // row 512B
    const char* Bsrc = (const char*)(xT + ((size_t)b * N_ + n0) * C_);

    // staging lane constants (chunk = 8 rows x 128B)
    const int sr = lane >> 3;            // row within chunk
    const int sc = (lane & 7) << 4;      // byte col 0..127
    const int ssw = sc ^ (sr << 4);      // pre-swizzled source col

    f32x4 acc[4][4];
    #pragma unroll
    for (int i = 0; i < 4; i++)
        #pragma unroll
        for (int j = 0; j < 4; j++) acc[i][j] = (f32x4){0.f, 0.f, 0.f, 0.f};

    const int rsw = (ln & 7) << 4;       // reader-side XOR swizzle

#define PROJ_STAGE(bufofs, k0) do {                                          \
    _Pragma("unroll")                                                        \
    for (int r_ = 0; r_ < 4; r_++) {                                         \
        int c_   = (wv << 2) + r_;                                           \
        int row_ = (c_ << 3) + sr;                                           \
        gload_lds16(Asrc + (size_t)row_ * 512 + (k0) * 2 + ssw,              \
                    smem + (bufofs) + (c_ << 10));                           \
        gload_lds16(Bsrc + (size_t)row_ * 512 + (k0) * 2 + ssw,              \
                    smem + (bufofs) + 16384 + (c_ << 10));                   \
    }                                                                        \
} while (0)

    PROJ_STAGE(0, 0);
    int buf = 0;
    #pragma unroll
    for (int s = 0; s < 4; s++) {
        if (s < 3) {
            PROJ_STAGE(buf ^ 32768, (s + 1) * 64);
            asm volatile("s_waitcnt vmcnt(8)" ::: "memory");
        } else {
            asm volatile("s_waitcnt vmcnt(0)" ::: "memory");
        }
        __builtin_amdgcn_s_barrier();
        asm volatile("" ::: "memory");

        const char* Ab = smem + buf;
        const char* Bb = smem + buf + 16384;
        #pragma unroll
        for (int kk = 0; kk < 2; kk++) {
            s16x8 aW[4], bX[4];
            #pragma unroll
            for (int m4 = 0; m4 < 4; m4++)
                aW[m4] = *(const s16x8*)(Ab + ((wr * 64 + m4 * 16 + ln) << 7)
                                            + (((kk << 6) + (g4 << 4)) ^ rsw));
            #pragma unroll
            for (int nt = 0; nt < 4; nt++)
                bX[nt] = *(const s16x8*)(Bb + ((wc * 64 + nt * 16 + ln) << 7)
                                            + (((kk << 6) + (g4 << 4)) ^ rsw));
            __builtin_amdgcn_s_setprio(1);
            #pragma unroll
            for (int m4 = 0; m4 < 4; m4++)
                #pragma unroll
                for (int nt = 0; nt < 4; nt++)
                    acc[m4][nt] = __builtin_amdgcn_mfma_f32_16x16x32_bf16(
                        aW[m4], bX[nt], acc[m4][nt], 0, 0, 0);
            __builtin_amdgcn_s_setprio(0);
        }
        block_sync_lds();
        buf ^= 32768;
    }

    if (mt == 0) {
        // g: [CI][N], m-major
        ushort* ob = g + (size_t)b * CI_ * N_;
        #pragma unroll
        for (int m4 = 0; m4 < 4; m4++) {
            #pragma unroll
            for (int r = 0; r < 4; r++) {
                int m = wr * 64 + m4 * 16 + 4 * g4 + r;
                float bi = bcat[m];
                #pragma unroll
                for (int nt = 0; nt < 4; nt++) {
                    int n = n0 + wc * 64 + nt * 16 + ln;
                    ob[(size_t)m * N_ + n] = f2bf(acc[m4][nt][r] + bi);
                }
            }
        }
    } else {
        // tht/pht: [N][CI], transposed; pack 4 consecutive ci as ushort4
        ushort* ob = (mt == 1 ? tht : pht) + (size_t)b * N_ * CI_;
        const float* bb = bcat + mt * 128;
        #pragma unroll
        for (int m4 = 0; m4 < 4; m4++) {
            int mbase = wr * 64 + m4 * 16 + 4 * g4;
            #pragma unroll
            for (int nt = 0; nt < 4; nt++) {
                int n = n0 + wc * 64 + nt * 16 + ln;
                ushort v4[4];
                #pragma unroll
                for (int r = 0; r < 4; r++)
                    v4[r] = f2bf(acc[m4][nt][r] + bb[mbase + r]);
                *(ushort4*)&ob[(size_t)n * CI_ + mbase] = *(ushort4*)v4;
            }
        }
    }
#undef PROJ_STAGE
}

// ---------------------------------------------------------------------------
// MFMA flash attention (unchanged from R4: 48 us, no spill).
// ---------------------------------------------------------------------------
__device__ inline float build_pa(const f32x16& S, s16x8& f0, s16x8& f1) {
    unsigned w[8];
    #pragma unroll
    for (int e = 0; e < 8; e++)
        w[e] = pkbf(__expf(S[2 * e]), __expf(S[2 * e + 1]));
    float ls = 0.f;
    #pragma unroll
    for (int e = 0; e < 8; e++)
        ls += __uint_as_float(w[e] << 16) + __uint_as_float(w[e] & 0xFFFF0000u);
    plswap(w[0], w[2]);
    plswap(w[1], w[3]);
    plswap(w[4], w[6]);
    plswap(w[5], w[7]);
    union { unsigned u[4]; s16x8 v; } A, B;
    A.u[0] = w[0]; A.u[1] = w[1]; A.u[2] = w[2]; A.u[3] = w[3];
    B.u[0] = w[4]; B.u[1] = w[5]; B.u[2] = w[6]; B.u[3] = w[7];
    f0 = A.v; f1 = B.v;
    return ls;
}

#define STAGE_KV(bufofs, jsrc) do {                                          \
    _Pragma("unroll")                                                        \
    for (int r_ = 0; r_ < 4; r_++) {                                         \
        int c_   = (wv << 2) + r_;                                           \
        int row_ = (c_ << 2) + kr;                                           \
        int src_ = (((jsrc) + row_) << 8) + (kc ^ ((row_ & 7) << 4));        \
        gload_lds16(kB + src_, smemB + (bufofs) + (c_ << 10));               \
    }                                                                        \
    _Pragma("unroll")                                                        \
    for (int r_ = 0; r_ < 4; r_++) {                                         \
        int c_   = (wv << 2) + r_;                                           \
        int row_ = (c_ << 3) + vr;                                           \
        int src_ = row_ * (N_ * 2) + ((jsrc) << 1) + (vc ^ ((row_ & 7) << 4));\
        gload_lds16(vB + src_, smemB + (bufofs) + 16384 + (c_ << 10));       \
    }                                                                        \
} while (0)

#define NC_ 4
#define JC_ (N_ / NC_)

__global__ __launch_bounds__(256, 2) void attn_mfma_kernel(
    const ushort* __restrict__ qn,   // [B][N][CI]
    const ushort* __restrict__ kn,   // [B][N][CI]
    const ushort* __restrict__ vm,   // [B][CI][N]
    ushort* __restrict__ Opart,      // [NC][B][N][CI] bf16 (unnormalized)
    float* __restrict__ lbuf)        // [NC][B][N] row sums
{
    __shared__ __align__(16) char smemB[65536];

    constexpr int NI = N_ / 128;
    constexpr int nb = NI * NC_ * B_;
    int flat = (blockIdx.z * NC_ + blockIdx.y) * NI + blockIdx.x;
    int nf   = (flat & 7) * (nb / 8) + (flat >> 3);
    const int i0    = (nf % NI) * 128;
    const int chunk = (nf / NI) % NC_;
    const int b     = nf / (NI * NC_);
    const int jbase = chunk * JC_;

    const int t    = threadIdx.x;
    const int wv   = t >> 6;
    const int lane = t & 63;
    const int n32  = lane & 31;
    const int h    = lane >> 5;
    const int swz  = (n32 & 7) << 4;

    const char* kB = (const char*)(kn + (size_t)b * N_ * CI_);
    const char* vB = (const char*)(vm + (size_t)b * CI_ * N_);

    const ushort* qb = qn + ((size_t)b * N_ + i0) * CI_;
    s16x8 aQ[8];
    #pragma unroll
    for (int kk = 0; kk < 8; kk++)
        aQ[kk] = *(const s16x8*)(qb + (size_t)(32 * wv + n32) * CI_ + 16 * kk + 8 * h);

    f32x16 Oacc[4];
    #pragma unroll
    for (int dt = 0; dt < 4; dt++)
        #pragma unroll
        for (int e = 0; e < 16; e++) Oacc[dt][e] = 0.f;
    float lsum = 0.f;

    const int kr = lane >> 4;
    const int kc = (lane & 15) << 4;
    const int vr = lane >> 3;
    const int vc = (lane & 7) << 4;

    STAGE_KV(0, jbase);
    int buf = 0;
    for (int jt = jbase; jt < jbase + JC_; jt += 64) {
        if (jt + 64 < jbase + JC_) {
            STAGE_KV(buf ^ 32768, jt + 64);
            asm volatile("s_waitcnt vmcnt(8)" ::: "memory");
        } else {
            asm volatile("s_waitcnt vmcnt(0)" ::: "memory");
        }
        __builtin_amdgcn_s_barrier();
        asm volatile("" ::: "memory");

        const char* Kc = smemB + buf;
        const char* Vc = smemB + buf + 16384;

        s16x8 pa[4];
        {
            f32x16 S0;
            #pragma unroll
            for (int e = 0; e < 16; e++) S0[e] = 0.f;
            __builtin_amdgcn_s_setprio(1);
            #pragma unroll
            for (int kk = 0; kk < 8; kk++) {
                s16x8 aK = *(const s16x8*)(Kc + (n32 << 8) + (((kk << 5) + (h << 4)) ^ swz));
                S0 = __builtin_amdgcn_mfma_f32_32x32x16_bf16(aK, aQ[kk], S0, 0, 0, 0);
            }
            __builtin_amdgcn_s_setprio(0);
            lsum += build_pa(S0, pa[0], pa[1]);
        }
        {
            f32x16 S1;
            #pragma unroll
            for (int e = 0; e < 16; e++) S1[e] = 0.f;
            __builtin_amdgcn_s_setprio(1);
            #pragma unroll
            for (int kk = 0; kk < 8; kk++) {
                s16x8 aK = *(const s16x8*)(Kc + 8192 + (n32 << 8) + (((kk << 5) + (h << 4)) ^ swz));
                S1 = __builtin_amdgcn_mfma_f32_32x32x16_bf16(aK, aQ[kk], S1, 0, 0, 0);
            }
            __builtin_amdgcn_s_setprio(0);
            lsum += build_pa(S1, pa[2], pa[3]);
        }

        __builtin_amdgcn_s_setprio(1);
        #pragma unroll
        for (int dt = 0; dt < 4; dt++) {
            #pragma unroll
            for (int kk = 0; kk < 4; kk++) {
                s16x8 bV = *(const s16x8*)(Vc + ((32 * dt + n32) << 7)
                                              + (((kk << 5) + (h << 4)) ^ swz));
                Oacc[dt] = __builtin_amdgcn_mfma_f32_32x32x16_bf16(pa[kk], bV, Oacc[dt], 0, 0, 0);
            }
        }
        __builtin_amdgcn_s_setprio(0);

        block_sync_lds();
        buf ^= 32768;
    }

    ushort* Ob = Opart + (size_t)chunk * (B_ * N_ * CI_) + ((size_t)b * N_ + i0) * CI_;
    #pragma unroll
    for (int rg = 0; rg < 16; rg++) {
        int R = (rg & 3) + 8 * (rg >> 2) + 4 * h;
        int q = 32 * wv + R;
        #pragma unroll
        for (int dt = 0; dt < 4; dt++)
            Ob[(size_t)q * CI_ + 32 * dt + n32] = f2bf(Oacc[dt][rg]);
    }
    float ot  = __shfl_xor(lsum, 32);
    float tot = lsum + ot;
    if (h == 0)
        lbuf[((size_t)chunk * B_ + b) * N_ + i0 + 32 * wv + n32] = tot;
}

// ---------------------------------------------------------------------------
// Output GEMM v2: 128x128 tile, K=128 staged in ONE shot (no K loop).
// W (32 KB) via gload_lds w/ 16-slot swizzle (conflict-free A reads);
// Y (32 KB) reg-staged with fused 4-chunk combine + 1/l from LDS.
// One vmcnt(0)+barrier, then 64 MFMA/wave straight. Grid (N/128, 2, B).
// ---------------------------------------------------------------------------
__global__ __launch_bounds__(256, 2) void outgemm_kernel(
    const ushort* __restrict__ Wobf, const float* __restrict__ bo,
    const ushort* __restrict__ Opart, const float* __restrict__ lbuf,
    const float* __restrict__ x, float* __restrict__ out)
{
    __shared__ __align__(16) char smem[65536];   // W 32KB | Y 32KB
    __shared__ float invL[128];
    const int b = blockIdx.z, m0 = blockIdx.y * 128, n0 = blockIdx.x * 128;
    const int t = threadIdx.x, wv = t >> 6, lane = t & 63;
    const int wr = wv >> 1, wc = wv & 1;
    const int g4 = lane >> 4, ln = lane & 15;
    const size_t cs = (size_t)B_ * N_ * CI_;     // Opart chunk stride

    // ---- issue W staging: 128 rows x 256B = 32 chunks; 8 per wave.
    // chunk covers 4 rows; source pre-swizzled with 16-slot XOR.
    {
        const char* Wsrc = (const char*)(Wobf + (size_t)m0 * CI_);
        int srl = lane >> 4;                 // row within chunk (0..3)
        int scl = (lane & 15) << 4;          // byte col 0..240
        #pragma unroll
        for (int r = 0; r < 8; r++) {
            int c   = (wv << 3) + r;
            int row = (c << 2) + srl;
            gload_lds16(Wsrc + (size_t)row * 256 + (scl ^ ((row & 15) << 4)),
                        smem + (c << 10));
        }
    }

    // ---- 1/l per row (shared by both K halves of the combine)
    if (t < 128) {
        float ls = 0.f;
        #pragma unroll
        for (int c = 0; c < NC_; c++)
            ls += lbuf[((size_t)c * B_ + b) * N_ + n0 + t];
        invL[t] = 1.0f / ls;
    }
    block_sync_lds();   // invL visible (W DMAs still in flight)

    // ---- stage Y = (sum_c Oc) * invL : 128 rows x 256B = 2048 chunks of
    // 16B; 8 per thread. ds_write_b128 at 16-slot-swizzled position.
    {
        #pragma unroll
        for (int r = 0; r < 8; r++) {
            int c   = t + 256 * r;
            int row = c >> 4;                 // 0..127
            int col = (c & 15) << 4;          // byte col (semantic d*2)
            size_t obase = ((size_t)b * N_ + n0 + row) * CI_ + (c & 15) * 8;
            float inv = invL[row];
            float osum[8];
            #pragma unroll
            for (int u = 0; u < 8; u++) osum[u] = 0.f;
            #pragma unroll
            for (int cc = 0; cc < NC_; cc++) {
                ushort oc[8];
                *(uint4*)oc = *(const uint4*)&Opart[(size_t)cc * cs + obase];
                #pragma unroll
                for (int u = 0; u < 8; u++) osum[u] += bf2f(oc[u]);
            }
            ushort yo[8];
            #pragma unroll
            for (int u = 0; u < 8; u++) yo[u] = f2bf(osum[u] * inv);
            *(uint4*)(smem + 32768 + row * 256 + (col ^ ((row & 15) << 4))) = *(uint4*)yo;
        }
    }
    asm volatile("s_waitcnt vmcnt(0)" ::: "memory");   // W arrived
    block_sync_lds();                                  // Y visible

    // ---- compute: C[m][n] = sum_d W[m][d] Y[n][d], 64 MFMA/wave
    f32x4 acc[4][4];
    #pragma unroll
    for (int i = 0; i < 4; i++)
        #pragma unroll
        for (int j = 0; j < 4; j++) acc[i][j] = (f32x4){0.f, 0.f, 0.f, 0.f};

    const int rsw = ln << 4;   // 16-slot reader swizzle (row&15 == ln)
    #pragma unroll
    for (int kk = 0; kk < 4; kk++) {
        s16x8 aW[4], bY[4];
        #pragma unroll
        for (int m4 = 0; m4 < 4; m4++)
            aW[m4] = *(const s16x8*)(smem + ((wr * 64 + m4 * 16 + ln) << 8)
                                          + (((kk << 6) + (g4 << 4)) ^ rsw));
        #pragma unroll
        for (int nt = 0; nt < 4; nt++)
            bY[nt] = *(const s16x8*)(smem + 32768 + ((wc * 64 + nt * 16 + ln) << 8)
                                          + (((kk << 6) + (g4 << 4)) ^ rsw));
        __builtin_amdgcn_s_setprio(1);
        #pragma unroll
        for (int m4 = 0; m4 < 4; m4++)
            #pragma unroll
            for (int nt = 0; nt < 4; nt++)
                acc[m4][nt] = __builtin_amdgcn_mfma_f32_16x16x32_bf16(
                    aW[m4], bY[nt], acc[m4][nt], 0, 0, 0);
        __builtin_amdgcn_s_setprio(0);
    }

    // ---- epilogue: out = acc + bo + x
    float* outb = out + (size_t)b * C_ * N_;
    const float* xb = x + (size_t)b * C_ * N_;
    #pragma unroll
    for (int m4 = 0; m4 < 4; m4++) {
        #pragma unroll
        for (int r = 0; r < 4; r++) {
            int m = m0 + wr * 64 + m4 * 16 + 4 * g4 + r;
            float bi = bo[m];
            #pragma unroll
            for (int nt = 0; nt < 4; nt++) {
                size_t idx = (size_t)m * N_ + n0 + wc * 64 + nt * 16 + ln;
                outb[idx] = acc[m4][nt][r] + bi + xb[idx];
            }
        }
    }
}

// ---------------------------------------------------------------------------
extern "C" void kernel_launch(void* const* d_in, const int* in_sizes, int n_in,
                              void* d_out, int out_size, void* d_ws, size_t ws_size,
                              hipStream_t stream) {
    const float* x  = (const float*)d_in[0];
    const float* Wg = (const float*)d_in[1];
    const float* bg = (const float*)d_in[2];
    const float* Wt = (const float*)d_in[3];
    const float* bt = (const float*)d_in[4];
    const float* Wp = (const float*)d_in[5];
    const float* bp = (const float*)d_in[6];
    const float* Wo = (const float*)d_in[7];
    const float* bo = (const float*)d_in[8];
    float* out = (float*)d_out;

    // ws layout (bytes), NC=4. xT (8 MB) dead after proj; Opart aliases it.
    char* w = (char*)d_ws;
    ushort* xT    = (ushort*)w;                   // [B][N][C]  bf16, 8 MB
    ushort* Opart = (ushort*)w;                   // [4][B][N][CI] bf16, 16 MB
    ushort* g     = (ushort*)(w + 16777216);      // [B][CI][N] bf16, 4 MB
    ushort* tht   = (ushort*)(w + 20971520);      // [B][N][CI] bf16, 4 MB
    ushort* pht   = (ushort*)(w + 25165824);      // [B][N][CI] bf16, 4 MB
    ushort* Wcat  = (ushort*)(w + 29360128);      // [384][256] bf16
    ushort* Wobf  = (ushort*)(w + 29556736);      // [256][128] bf16
    float*  bcat  = (float*) (w + 29622272);      // [384]
    float*  lbuf  = (float*) (w + 29623808);      // [4][B][N] fp32, 256 KB

    dim3 blk(256);
    prep_kernel<<<1536, blk, 0, stream>>>(Wg, Wt, Wp, Wo, bg, bt, bp,
                                          Wcat, Wobf, bcat, x, xT);
    proj_kernel<<<dim3(N_ / 128, 3, B_), blk, 0, stream>>>(Wcat, bcat, xT, g, tht, pht);
    attn_mfma_kernel<<<dim3(N_ / 128, NC_, B_), blk, 0, stream>>>(tht, pht, g, Opart, lbuf);
    outgemm_kernel<<<dim3(N_ / 128, C_ / 128, B_), blk, 0, stream>>>(Wobf, bo, Opart, lbuf, x, out);
}